// Round 2
// baseline (359.880 us; speedup 1.0000x reference)
//
#include <hip/hip_runtime.h>
#include <hip/hip_bf16.h>

typedef __attribute__((ext_vector_type(8))) short bf16x8;
typedef __attribute__((ext_vector_type(4))) float f32x4;

#define NB 8
#define NT 2048
#define ND 768
#define NH 12
#define SCALE 0.125f

__device__ __forceinline__ ushort f2b(float f) {
  __hip_bfloat16 h = __float2bfloat16(f);
  return __builtin_bit_cast(ushort, h);
}

// ---------------- k0: Wv (V half of Wkv) -> bf16 ----------------
__global__ __launch_bounds__(256) void k0_prep(const float* __restrict__ Wkv,
                                               ushort* __restrict__ Wvb) {
  int i = blockIdx.x * 256 + threadIdx.x;  // over 768*768
  int c = i / ND, e = i % ND;
  Wvb[i] = f2b(Wkv[(size_t)c * 1536 + 768 + e]);
}

// ---------------- k1a: q,k projections (first 64 rows) ----------------
// qk layout: [which(0=q,1=k)][b][64][768] f32
__global__ __launch_bounds__(512) void k1a_qk(
    const float* __restrict__ x, const float* __restrict__ y,
    const float* __restrict__ Wq, const float* __restrict__ bq,
    const float* __restrict__ Wkv, const float* __restrict__ bkv,
    float* __restrict__ qk) {
  int h = blockIdx.x;
  int b = blockIdx.y;
  int which = blockIdx.z;
  const float* src = which ? y : x;
  __shared__ float sA[64][68];
  __shared__ float sB[64][68];
  int tid = threadIdx.x;
  int tx = tid & 15;   // col group (x4)
  int ty = tid >> 4;   // row group (0..31, x2)
  float acc[2][4] = {{0.f,0.f,0.f,0.f},{0.f,0.f,0.f,0.f}};
  for (int kt = 0; kt < 12; ++kt) {
    __syncthreads();
    #pragma unroll
    for (int p = 0; p < 8; ++p) {
      int i = p * 512 + tid;  // 0..4095
      int r = i >> 6, c = i & 63;
      sA[r][c] = src[(size_t)b * NT * ND + r * ND + kt * 64 + c];
      sB[r][c] = which ? Wkv[(size_t)(kt * 64 + r) * 1536 + h * 64 + c]
                       : Wq[(size_t)(kt * 64 + r) * ND + h * 64 + c];
    }
    __syncthreads();
    #pragma unroll 8
    for (int kk = 0; kk < 64; ++kk) {
      float4 bv = *(const float4*)&sB[kk][tx * 4];
      float a0 = sA[ty * 2 + 0][kk];
      float a1 = sA[ty * 2 + 1][kk];
      acc[0][0] += a0 * bv.x; acc[0][1] += a0 * bv.y;
      acc[0][2] += a0 * bv.z; acc[0][3] += a0 * bv.w;
      acc[1][0] += a1 * bv.x; acc[1][1] += a1 * bv.y;
      acc[1][2] += a1 * bv.z; acc[1][3] += a1 * bv.w;
    }
  }
  const float* bias = which ? bkv : bq;
  float* dst = qk + ((size_t)which * NB + b) * 64 * ND;
  #pragma unroll
  for (int i2 = 0; i2 < 2; ++i2)
    #pragma unroll
    for (int j = 0; j < 4; ++j)
      dst[(ty * 2 + i2) * ND + h * 64 + tx * 4 + j] =
          acc[i2][j] + bias[h * 64 + tx * 4 + j];
}

// ---------------- k1b: scores + softmax -> attn (B,12,64,64) f32 ----------------
__global__ __launch_bounds__(256) void k1b_attn(const float* __restrict__ qk,
                                                float* __restrict__ attn) {
  int h = blockIdx.x, b = blockIdx.y;
  __shared__ float qs[64][68];
  __shared__ float ks[64][68];
  __shared__ float sc[64][68];
  __shared__ float rm[64], rs[64];
  int tid = threadIdx.x;
  #pragma unroll
  for (int p = 0; p < 16; ++p) {
    int i = p * 256 + tid;
    int r = i >> 6, c = i & 63;
    qs[r][c] = qk[(size_t)b * 64 * ND + r * ND + h * 64 + c];
    ks[r][c] = qk[(size_t)(NB + b) * 64 * ND + r * ND + h * 64 + c];
  }
  __syncthreads();
  int tx = tid & 15, ty = tid >> 4;
  float a[4][4] = {};
  #pragma unroll 8
  for (int kk = 0; kk < 64; ++kk) {
    float qv[4], kv[4];
    #pragma unroll
    for (int i = 0; i < 4; ++i) qv[i] = qs[ty * 4 + i][kk];
    #pragma unroll
    for (int j = 0; j < 4; ++j) kv[j] = ks[tx * 4 + j][kk];
    #pragma unroll
    for (int i = 0; i < 4; ++i)
      #pragma unroll
      for (int j = 0; j < 4; ++j) a[i][j] += qv[i] * kv[j];
  }
  #pragma unroll
  for (int i = 0; i < 4; ++i)
    #pragma unroll
    for (int j = 0; j < 4; ++j)
      sc[ty * 4 + i][tx * 4 + j] = a[i][j] * SCALE;
  __syncthreads();
  if (tid < 64) {
    float m = -1e30f;
    for (int z = 0; z < 64; ++z) m = fmaxf(m, sc[tid][z]);
    float s = 0.f;
    for (int z = 0; z < 64; ++z) s += expf(sc[tid][z] - m);
    rm[tid] = m;
    rs[tid] = 1.0f / s;
  }
  __syncthreads();
  #pragma unroll
  for (int p = 0; p < 16; ++p) {
    int i = p * 256 + tid;
    int r = i >> 6, c = i & 63;
    attn[((size_t)(b * NH + h) * 64 + r) * 64 + c] =
        expf(sc[r][c] - rm[r]) * rs[r];
  }
}

// ---------------- k2: PT[b][j][h*64+d] = sum_s attn[b,h,d,s]*Wo[h*64+s][j] (bf16) ----------------
__global__ __launch_bounds__(256) void k2_pt(const float* __restrict__ attn,
                                             const float* __restrict__ Wo,
                                             ushort* __restrict__ PT) {
  int jt = blockIdx.x, h = blockIdx.y, b = blockIdx.z;
  __shared__ float at[64][64];
  int tid = threadIdx.x;
  #pragma unroll
  for (int p = 0; p < 16; ++p) {
    int i = p * 256 + tid;
    int d = i >> 6, s = i & 63;
    at[d][s] = attn[((size_t)(b * NH + h) * 64 + d) * 64 + s];
  }
  __syncthreads();
  int tx = tid & 31;  // j group (x4)
  int ty = tid >> 5;  // d group (x8)
  int j0 = jt * 128 + tx * 4;
  float acc[8][4] = {};
  for (int s = 0; s < 64; ++s) {
    float4 w = *(const float4*)&Wo[(size_t)(h * 64 + s) * ND + j0];
    #pragma unroll
    for (int dd = 0; dd < 8; ++dd) {
      float av = at[ty * 8 + dd][s];
      acc[dd][0] += av * w.x; acc[dd][1] += av * w.y;
      acc[dd][2] += av * w.z; acc[dd][3] += av * w.w;
    }
  }
  #pragma unroll
  for (int jj = 0; jj < 4; ++jj) {
    ushort tmp[8];
    #pragma unroll
    for (int dd = 0; dd < 8; ++dd) tmp[dd] = f2b(acc[dd][jj]);
    *(uint4*)&PT[(size_t)b * ND * ND + (size_t)(j0 + jj) * ND + h * 64 + ty * 8] =
        *(const uint4*)tmp;
  }
}

// ---------------- k2b: cvec[b][j] = sum_e (bv@BD)[e]*Wo[e][j] + bo[j] ----------------
__global__ __launch_bounds__(256) void k2b_cvec(const float* __restrict__ attn,
                                                const float* __restrict__ Wo,
                                                const float* __restrict__ bkv,
                                                const float* __restrict__ bo,
                                                float* __restrict__ cvec) {
  int b = blockIdx.x;
  __shared__ float bvA[768];
  int tid = threadIdx.x;
  for (int i = tid; i < ND; i += 256) {
    int h = i >> 6, s = i & 63;
    const float* at = attn + (size_t)(b * NH + h) * 64 * 64;
    float acc = 0.f;
    for (int d = 0; d < 64; ++d) acc += bkv[768 + h * 64 + d] * at[d * 64 + s];
    bvA[i] = acc;
  }
  __syncthreads();
  for (int j = tid; j < ND; j += 256) {
    float acc = bo[j];
    #pragma unroll 4
    for (int e = 0; e < ND; ++e) acc += bvA[e] * Wo[(size_t)e * ND + j];
    cvec[b * ND + j] = acc;
  }
}

// ---------------- k3: MT[b][j][c] = sum_e PT[b][j][e] * Wvb[c][e] (bf16 MFMA) ----------------
__global__ __launch_bounds__(256) void k3_gemm(const ushort* __restrict__ PT,
                                               const ushort* __restrict__ Wvb,
                                               ushort* __restrict__ MT) {
  int b = blockIdx.z;
  int rowt = blockIdx.y;  // j tile
  int colt = blockIdx.x;  // c tile
  const ushort* A = PT + (size_t)b * ND * ND + (size_t)rowt * 128 * ND;
  const ushort* Bt = Wvb + (size_t)colt * 128 * ND;
  ushort* Cout = MT + (size_t)b * ND * ND + (size_t)rowt * 128 * ND + colt * 128;

  __shared__ ushort As[128 * 32];
  __shared__ ushort Bs[128 * 32];
  int tid = threadIdx.x;
  int wid = tid >> 6;
  int lane = tid & 63;
  int wr = (wid >> 1) * 64;
  int wc = (wid & 1) * 64;
  int l15 = lane & 15;
  int l4 = lane >> 4;

  f32x4 acc[4][4];
  #pragma unroll
  for (int mi = 0; mi < 4; ++mi)
    #pragma unroll
    for (int ni = 0; ni < 4; ++ni) acc[mi][ni] = {0.f, 0.f, 0.f, 0.f};

  for (int k0 = 0; k0 < ND; k0 += 32) {
    __syncthreads();
    // 128 rows x 32 ushort per tile; each uint4 = 8 ushorts -> 4 chunks/row,
    // 512 chunks total for A and for B.
    #pragma unroll
    for (int p = 0; p < 2; ++p) {
      int i = p * 256 + tid;  // 0..511
      int row = i >> 2;       // 0..127
      int kc = (i & 3) * 8;   // 0,8,16,24
      *(uint4*)&As[row * 32 + kc] = *(const uint4*)&A[(size_t)row * ND + k0 + kc];
      *(uint4*)&Bs[row * 32 + kc] = *(const uint4*)&Bt[(size_t)row * ND + k0 + kc];
    }
    __syncthreads();
    bf16x8 af[4], bfr[4];
    #pragma unroll
    for (int mi = 0; mi < 4; ++mi)
      af[mi] = *(const bf16x8*)&As[(wr + mi * 16 + l15) * 32 + l4 * 8];
    #pragma unroll
    for (int ni = 0; ni < 4; ++ni)
      bfr[ni] = *(const bf16x8*)&Bs[(wc + ni * 16 + l15) * 32 + l4 * 8];
    #pragma unroll
    for (int mi = 0; mi < 4; ++mi)
      #pragma unroll
      for (int ni = 0; ni < 4; ++ni)
        acc[mi][ni] = __builtin_amdgcn_mfma_f32_16x16x32_bf16(af[mi], bfr[ni],
                                                              acc[mi][ni], 0, 0, 0);
  }
  #pragma unroll
  for (int mi = 0; mi < 4; ++mi)
    #pragma unroll
    for (int ni = 0; ni < 4; ++ni)
      #pragma unroll
      for (int j = 0; j < 4; ++j) {
        int r = wr + mi * 16 + l4 * 4 + j;
        int c = wc + ni * 16 + l15;
        Cout[(size_t)r * ND + c] = f2b(acc[mi][ni][j]);
      }
}

// ---------------- k4: out[b] = y[b] @ M_b + cvec[b] + y[b] ----------------
__global__ __launch_bounds__(256) void k4_gemm(const float* __restrict__ y,
                                               const ushort* __restrict__ MT,
                                               const float* __restrict__ cvec,
                                               float* __restrict__ out) {
  int b = blockIdx.z;
  int rowt = blockIdx.y;  // n tile (16)
  int colt = blockIdx.x;  // j tile (6)
  const float* A = y + (size_t)b * NT * ND + (size_t)rowt * 128 * ND;
  const ushort* Bt = MT + (size_t)b * ND * ND + (size_t)colt * 128 * ND;
  const float* Ysrc = y + (size_t)b * NT * ND;
  float* Out = out + (size_t)b * NT * ND;

  __shared__ ushort As[128 * 32];
  __shared__ ushort Bs[128 * 32];
  int tid = threadIdx.x;
  int wid = tid >> 6;
  int lane = tid & 63;
  int wr = (wid >> 1) * 64;
  int wc = (wid & 1) * 64;
  int l15 = lane & 15;
  int l4 = lane >> 4;

  f32x4 acc[4][4];
  #pragma unroll
  for (int mi = 0; mi < 4; ++mi)
    #pragma unroll
    for (int ni = 0; ni < 4; ++ni) acc[mi][ni] = {0.f, 0.f, 0.f, 0.f};

  for (int k0 = 0; k0 < ND; k0 += 32) {
    __syncthreads();
    // A: 128 rows x 32 f32 -> bf16 convert in-register (1024 float4 chunks)
    #pragma unroll
    for (int p = 0; p < 4; ++p) {
      int i = p * 256 + tid;  // 0..1023
      int row = i >> 3;       // 0..127
      int kc = (i & 7) * 4;   // 0,4,...,28
      float4 v = *(const float4*)&A[(size_t)row * ND + k0 + kc];
      ushort4 u;
      u.x = f2b(v.x); u.y = f2b(v.y); u.z = f2b(v.z); u.w = f2b(v.w);
      *(ushort4*)&As[row * 32 + kc] = u;
    }
    // B: bf16 direct (512 uint4 chunks)
    #pragma unroll
    for (int p = 0; p < 2; ++p) {
      int i = p * 256 + tid;  // 0..511
      int row = i >> 2;       // 0..127
      int kc = (i & 3) * 8;   // 0,8,16,24
      *(uint4*)&Bs[row * 32 + kc] = *(const uint4*)&Bt[(size_t)row * ND + k0 + kc];
    }
    __syncthreads();
    bf16x8 af[4], bfr[4];
    #pragma unroll
    for (int mi = 0; mi < 4; ++mi)
      af[mi] = *(const bf16x8*)&As[(wr + mi * 16 + l15) * 32 + l4 * 8];
    #pragma unroll
    for (int ni = 0; ni < 4; ++ni)
      bfr[ni] = *(const bf16x8*)&Bs[(wc + ni * 16 + l15) * 32 + l4 * 8];
    #pragma unroll
    for (int mi = 0; mi < 4; ++mi)
      #pragma unroll
      for (int ni = 0; ni < 4; ++ni)
        acc[mi][ni] = __builtin_amdgcn_mfma_f32_16x16x32_bf16(af[mi], bfr[ni],
                                                              acc[mi][ni], 0, 0, 0);
  }
  #pragma unroll
  for (int mi = 0; mi < 4; ++mi)
    #pragma unroll
    for (int ni = 0; ni < 4; ++ni) {
      int c = wc + ni * 16 + l15;
      int gc = colt * 128 + c;
      float cv = cvec[b * ND + gc];
      #pragma unroll
      for (int j = 0; j < 4; ++j) {
        int r = wr + mi * 16 + l4 * 4 + j;
        int gr = rowt * 128 + r;
        Out[(size_t)gr * ND + gc] = acc[mi][ni][j] + cv + Ysrc[(size_t)gr * ND + gc];
      }
    }
}

extern "C" void kernel_launch(void* const* d_in, const int* in_sizes, int n_in,
                              void* d_out, int out_size, void* d_ws, size_t ws_size,
                              hipStream_t stream) {
  const float* x = (const float*)d_in[0];
  const float* y = (const float*)d_in[1];
  const float* Wq = (const float*)d_in[2];
  const float* bq = (const float*)d_in[3];
  const float* Wkv = (const float*)d_in[4];
  const float* bkv = (const float*)d_in[5];
  const float* Wo = (const float*)d_in[6];
  const float* bo = (const float*)d_in[7];
  float* out = (float*)d_out;

  char* ws = (char*)d_ws;
  float* qk    = (float*)(ws + 0);          // 2*8*64*768*4  = 3,145,728
  float* attn  = (float*)(ws + 3145728);    // 8*12*64*64*4  = 1,572,864
  float* cvec  = (float*)(ws + 4718592);    // 8*768*4       = 24,576
  ushort* Wvb  = (ushort*)(ws + 4743168);   // 768*768*2     = 1,179,648
  ushort* PT   = (ushort*)(ws + 5922816);   // 8*768*768*2   = 9,437,184
  ushort* MT   = (ushort*)(ws + 15360000);  // 8*768*768*2   = 9,437,184
                                            // total 24,797,184 bytes

  k0_prep<<<dim3(2304), 256, 0, stream>>>(Wkv, Wvb);
  k1a_qk<<<dim3(NH, NB, 2), 512, 0, stream>>>(x, y, Wq, bq, Wkv, bkv, qk);
  k1b_attn<<<dim3(NH, NB), 256, 0, stream>>>(qk, attn);
  k2_pt<<<dim3(6, NH, NB), 256, 0, stream>>>(attn, Wo, PT);
  k2b_cvec<<<dim3(NB), 256, 0, stream>>>(attn, Wo, bkv, bo, cvec);
  k3_gemm<<<dim3(6, 6, NB), 256, 0, stream>>>(PT, Wvb, MT);
  k4_gemm<<<dim3(6, 16, NB), 256, 0, stream>>>(y, MT, cvec, out);
}

// Round 3
// 185.034 us; speedup vs baseline: 1.9449x; 1.9449x over previous
//
#include <hip/hip_runtime.h>
#include <hip/hip_bf16.h>

typedef __attribute__((ext_vector_type(8))) short bf16x8;
typedef __attribute__((ext_vector_type(4))) float f32x4;

#define NB 8
#define NT 2048
#define ND 768
#define NH 12
#define SCALE 0.125f

__device__ __forceinline__ ushort f2b(float f) {
  __hip_bfloat16 h = __float2bfloat16(f);
  return __builtin_bit_cast(ushort, h);
}

// ---------------- k0: Wv (V half of Wkv) -> bf16 ----------------
__global__ __launch_bounds__(256) void k0_prep(const float* __restrict__ Wkv,
                                               ushort* __restrict__ Wvb) {
  int i = blockIdx.x * 256 + threadIdx.x;  // over 768*768
  int c = i / ND, e = i % ND;
  Wvb[i] = f2b(Wkv[(size_t)c * 1536 + 768 + e]);
}

// ---------------- k1a: q,k projections (first 64 rows) ----------------
// qk layout: [which(0=q,1=k)][b][64][768] f32
__global__ __launch_bounds__(512) void k1a_qk(
    const float* __restrict__ x, const float* __restrict__ y,
    const float* __restrict__ Wq, const float* __restrict__ bq,
    const float* __restrict__ Wkv, const float* __restrict__ bkv,
    float* __restrict__ qk) {
  int h = blockIdx.x;
  int b = blockIdx.y;
  int which = blockIdx.z;
  const float* src = which ? y : x;
  __shared__ float sA[64][68];
  __shared__ float sB[64][68];
  int tid = threadIdx.x;
  int tx = tid & 15;   // col group (x4)
  int ty = tid >> 4;   // row group (0..31, x2)
  float acc[2][4] = {{0.f,0.f,0.f,0.f},{0.f,0.f,0.f,0.f}};
  for (int kt = 0; kt < 12; ++kt) {
    __syncthreads();
    #pragma unroll
    for (int p = 0; p < 8; ++p) {
      int i = p * 512 + tid;  // 0..4095
      int r = i >> 6, c = i & 63;
      sA[r][c] = src[(size_t)b * NT * ND + r * ND + kt * 64 + c];
      sB[r][c] = which ? Wkv[(size_t)(kt * 64 + r) * 1536 + h * 64 + c]
                       : Wq[(size_t)(kt * 64 + r) * ND + h * 64 + c];
    }
    __syncthreads();
    #pragma unroll 8
    for (int kk = 0; kk < 64; ++kk) {
      float4 bv = *(const float4*)&sB[kk][tx * 4];
      float a0 = sA[ty * 2 + 0][kk];
      float a1 = sA[ty * 2 + 1][kk];
      acc[0][0] += a0 * bv.x; acc[0][1] += a0 * bv.y;
      acc[0][2] += a0 * bv.z; acc[0][3] += a0 * bv.w;
      acc[1][0] += a1 * bv.x; acc[1][1] += a1 * bv.y;
      acc[1][2] += a1 * bv.z; acc[1][3] += a1 * bv.w;
    }
  }
  const float* bias = which ? bkv : bq;
  float* dst = qk + ((size_t)which * NB + b) * 64 * ND;
  #pragma unroll
  for (int i2 = 0; i2 < 2; ++i2)
    #pragma unroll
    for (int j = 0; j < 4; ++j)
      dst[(ty * 2 + i2) * ND + h * 64 + tx * 4 + j] =
          acc[i2][j] + bias[h * 64 + tx * 4 + j];
}

// ---------------- k1b: scores + softmax -> attn (B,12,64,64) f32 ----------------
__global__ __launch_bounds__(256) void k1b_attn(const float* __restrict__ qk,
                                                float* __restrict__ attn) {
  int h = blockIdx.x, b = blockIdx.y;
  __shared__ float qs[64][68];
  __shared__ float ks[64][68];
  __shared__ float sc[64][68];
  __shared__ float rm[64], rs[64];
  int tid = threadIdx.x;
  #pragma unroll
  for (int p = 0; p < 16; ++p) {
    int i = p * 256 + tid;
    int r = i >> 6, c = i & 63;
    qs[r][c] = qk[(size_t)b * 64 * ND + r * ND + h * 64 + c];
    ks[r][c] = qk[(size_t)(NB + b) * 64 * ND + r * ND + h * 64 + c];
  }
  __syncthreads();
  int tx = tid & 15, ty = tid >> 4;
  float a[4][4] = {};
  #pragma unroll 8
  for (int kk = 0; kk < 64; ++kk) {
    float qv[4], kv[4];
    #pragma unroll
    for (int i = 0; i < 4; ++i) qv[i] = qs[ty * 4 + i][kk];
    #pragma unroll
    for (int j = 0; j < 4; ++j) kv[j] = ks[tx * 4 + j][kk];
    #pragma unroll
    for (int i = 0; i < 4; ++i)
      #pragma unroll
      for (int j = 0; j < 4; ++j) a[i][j] += qv[i] * kv[j];
  }
  #pragma unroll
  for (int i = 0; i < 4; ++i)
    #pragma unroll
    for (int j = 0; j < 4; ++j)
      sc[ty * 4 + i][tx * 4 + j] = a[i][j] * SCALE;
  __syncthreads();
  if (tid < 64) {
    float m = -1e30f;
    for (int z = 0; z < 64; ++z) m = fmaxf(m, sc[tid][z]);
    float s = 0.f;
    for (int z = 0; z < 64; ++z) s += expf(sc[tid][z] - m);
    rm[tid] = m;
    rs[tid] = 1.0f / s;
  }
  __syncthreads();
  #pragma unroll
  for (int p = 0; p < 16; ++p) {
    int i = p * 256 + tid;
    int r = i >> 6, c = i & 63;
    attn[((size_t)(b * NH + h) * 64 + r) * 64 + c] =
        expf(sc[r][c] - rm[r]) * rs[r];
  }
}

// ---------------- k2: PT[b][j][h*64+d] = sum_s attn[b,h,d,s]*Wo[h*64+s][j] (bf16) ----------------
__global__ __launch_bounds__(256) void k2_pt(const float* __restrict__ attn,
                                             const float* __restrict__ Wo,
                                             ushort* __restrict__ PT) {
  int jt = blockIdx.x, h = blockIdx.y, b = blockIdx.z;
  __shared__ float at[64][64];
  int tid = threadIdx.x;
  #pragma unroll
  for (int p = 0; p < 16; ++p) {
    int i = p * 256 + tid;
    int d = i >> 6, s = i & 63;
    at[d][s] = attn[((size_t)(b * NH + h) * 64 + d) * 64 + s];
  }
  __syncthreads();
  int tx = tid & 31;  // j group (x4)
  int ty = tid >> 5;  // d group (x8)
  int j0 = jt * 128 + tx * 4;
  float acc[8][4] = {};
  for (int s = 0; s < 64; ++s) {
    float4 w = *(const float4*)&Wo[(size_t)(h * 64 + s) * ND + j0];
    #pragma unroll
    for (int dd = 0; dd < 8; ++dd) {
      float av = at[ty * 8 + dd][s];
      acc[dd][0] += av * w.x; acc[dd][1] += av * w.y;
      acc[dd][2] += av * w.z; acc[dd][3] += av * w.w;
    }
  }
  #pragma unroll
  for (int jj = 0; jj < 4; ++jj) {
    ushort tmp[8];
    #pragma unroll
    for (int dd = 0; dd < 8; ++dd) tmp[dd] = f2b(acc[dd][jj]);
    *(uint4*)&PT[(size_t)b * ND * ND + (size_t)(j0 + jj) * ND + h * 64 + ty * 8] =
        *(const uint4*)tmp;
  }
}

// ---------------- k2b1: bvA[b][h*64+s] = sum_d bv[h*64+d]*attn[b,h,d,s] ----------------
__global__ __launch_bounds__(256) void k2b1_bva(const float* __restrict__ attn,
                                                const float* __restrict__ bkv,
                                                float* __restrict__ bvA) {
  int b = blockIdx.x;
  int tid = threadIdx.x;
  for (int i = tid; i < ND; i += 256) {
    int h = i >> 6, s = i & 63;
    const float* at = attn + (size_t)(b * NH + h) * 64 * 64;
    float acc = 0.f;
    #pragma unroll 8
    for (int d = 0; d < 64; ++d) acc += bkv[768 + h * 64 + d] * at[d * 64 + s];
    bvA[b * ND + i] = acc;
  }
}

// ---------------- k2b2: cvec[b][j] = sum_e bvA[b][e]*Wo[e][j] + bo[j] ----------------
// grid (6 jt, 8 b), 256 thr = 32 j-quads x 8 e-splits
__global__ __launch_bounds__(256) void k2b2_cvec(const float* __restrict__ bvA,
                                                 const float* __restrict__ Wo,
                                                 const float* __restrict__ bo,
                                                 float* __restrict__ cvec) {
  int jt = blockIdx.x, b = blockIdx.y;
  int tid = threadIdx.x;
  __shared__ float bl[768];
  __shared__ f32x4 red[256];
  for (int i = tid; i < ND; i += 256) bl[i] = bvA[b * ND + i];
  __syncthreads();
  int jq = tid & 31;   // j quad
  int es = tid >> 5;   // e split 0..7
  int j0 = jt * 128 + jq * 4;
  f32x4 acc = {0.f, 0.f, 0.f, 0.f};
  #pragma unroll 8
  for (int e = es * 96; e < es * 96 + 96; ++e) {
    float4 w = *(const float4*)&Wo[(size_t)e * ND + j0];
    float bv = bl[e];
    acc[0] += bv * w.x; acc[1] += bv * w.y;
    acc[2] += bv * w.z; acc[3] += bv * w.w;
  }
  red[tid] = acc;
  __syncthreads();
  if (tid < 32) {
    f32x4 s = red[tid];
    #pragma unroll
    for (int k = 1; k < 8; ++k) {
      f32x4 r = red[tid + 32 * k];
      s[0] += r[0]; s[1] += r[1]; s[2] += r[2]; s[3] += r[3];
    }
    #pragma unroll
    for (int c = 0; c < 4; ++c)
      cvec[b * ND + j0 + c] = s[c] + bo[j0 + c];
  }
}

// ---------------- k3: MT[b][j][c] = sum_e PT[b][j][e] * Wvb[c][e] (bf16 MFMA) ----------------
// LDS 16B-chunk XOR swizzle key = (row>>1)&3 on both write and read.
__global__ __launch_bounds__(256) void k3_gemm(const ushort* __restrict__ PT,
                                               const ushort* __restrict__ Wvb,
                                               ushort* __restrict__ MT) {
  int b = blockIdx.z;
  int rowt = blockIdx.y;  // j tile
  int colt = blockIdx.x;  // c tile
  const ushort* A = PT + (size_t)b * ND * ND + (size_t)rowt * 128 * ND;
  const ushort* Bt = Wvb + (size_t)colt * 128 * ND;
  ushort* Cout = MT + (size_t)b * ND * ND + (size_t)rowt * 128 * ND + colt * 128;

  __shared__ ushort As[128 * 32];
  __shared__ ushort Bs[128 * 32];
  int tid = threadIdx.x;
  int wid = tid >> 6;
  int lane = tid & 63;
  int wr = (wid >> 1) * 64;
  int wc = (wid & 1) * 64;
  int l15 = lane & 15;
  int l4 = lane >> 4;

  f32x4 acc[4][4];
  #pragma unroll
  for (int mi = 0; mi < 4; ++mi)
    #pragma unroll
    for (int ni = 0; ni < 4; ++ni) acc[mi][ni] = {0.f, 0.f, 0.f, 0.f};

  for (int k0 = 0; k0 < ND; k0 += 32) {
    __syncthreads();
    #pragma unroll
    for (int p = 0; p < 2; ++p) {
      int i = p * 256 + tid;  // 0..511
      int row = i >> 2;       // 0..127
      int ch = (i & 3) ^ ((row >> 1) & 3);  // swizzled 16B chunk
      *(uint4*)&As[row * 32 + ch * 8] = *(const uint4*)&A[(size_t)row * ND + k0 + (i & 3) * 8];
      *(uint4*)&Bs[row * 32 + ch * 8] = *(const uint4*)&Bt[(size_t)row * ND + k0 + (i & 3) * 8];
    }
    __syncthreads();
    bf16x8 af[4], bfr[4];
    #pragma unroll
    for (int mi = 0; mi < 4; ++mi) {
      int r = wr + mi * 16 + l15;
      af[mi] = *(const bf16x8*)&As[r * 32 + (l4 ^ ((r >> 1) & 3)) * 8];
    }
    #pragma unroll
    for (int ni = 0; ni < 4; ++ni) {
      int r = wc + ni * 16 + l15;
      bfr[ni] = *(const bf16x8*)&Bs[r * 32 + (l4 ^ ((r >> 1) & 3)) * 8];
    }
    #pragma unroll
    for (int mi = 0; mi < 4; ++mi)
      #pragma unroll
      for (int ni = 0; ni < 4; ++ni)
        acc[mi][ni] = __builtin_amdgcn_mfma_f32_16x16x32_bf16(af[mi], bfr[ni],
                                                              acc[mi][ni], 0, 0, 0);
  }
  #pragma unroll
  for (int mi = 0; mi < 4; ++mi)
    #pragma unroll
    for (int ni = 0; ni < 4; ++ni)
      #pragma unroll
      for (int j = 0; j < 4; ++j) {
        int r = wr + mi * 16 + l4 * 4 + j;
        int c = wc + ni * 16 + l15;
        Cout[(size_t)r * ND + c] = f2b(acc[mi][ni][j]);
      }
}

// ---------------- k4: out[b] = y[b] @ M_b + cvec[b] + y[b] ----------------
__global__ __launch_bounds__(256) void k4_gemm(const float* __restrict__ y,
                                               const ushort* __restrict__ MT,
                                               const float* __restrict__ cvec,
                                               float* __restrict__ out) {
  int b = blockIdx.z;
  int rowt = blockIdx.y;  // n tile (16)
  int colt = blockIdx.x;  // j tile (6)
  const float* A = y + (size_t)b * NT * ND + (size_t)rowt * 128 * ND;
  const ushort* Bt = MT + (size_t)b * ND * ND + (size_t)colt * 128 * ND;
  const float* Ysrc = y + (size_t)b * NT * ND;
  float* Out = out + (size_t)b * NT * ND;

  __shared__ ushort As[128 * 32];
  __shared__ ushort Bs[128 * 32];
  int tid = threadIdx.x;
  int wid = tid >> 6;
  int lane = tid & 63;
  int wr = (wid >> 1) * 64;
  int wc = (wid & 1) * 64;
  int l15 = lane & 15;
  int l4 = lane >> 4;

  f32x4 acc[4][4];
  #pragma unroll
  for (int mi = 0; mi < 4; ++mi)
    #pragma unroll
    for (int ni = 0; ni < 4; ++ni) acc[mi][ni] = {0.f, 0.f, 0.f, 0.f};

  for (int k0 = 0; k0 < ND; k0 += 32) {
    __syncthreads();
    // A: 128 rows x 32 f32 -> bf16 convert in-register (1024 ushort4 chunks of 8B)
    #pragma unroll
    for (int p = 0; p < 4; ++p) {
      int i = p * 256 + tid;  // 0..1023
      int row = i >> 3;       // 0..127
      int c8 = i & 7;         // 8B sub-chunk 0..7
      int ch16 = (c8 >> 1) ^ ((row >> 1) & 3);  // swizzled 16B chunk
      int kcw = ch16 * 8 + (c8 & 1) * 4;        // ushort offset in row
      float4 v = *(const float4*)&A[(size_t)row * ND + k0 + c8 * 4];
      ushort4 u;
      u.x = f2b(v.x); u.y = f2b(v.y); u.z = f2b(v.z); u.w = f2b(v.w);
      *(ushort4*)&As[row * 32 + kcw] = u;
    }
    // B: bf16 direct (512 uint4 chunks)
    #pragma unroll
    for (int p = 0; p < 2; ++p) {
      int i = p * 256 + tid;  // 0..511
      int row = i >> 2;       // 0..127
      int ch = (i & 3) ^ ((row >> 1) & 3);
      *(uint4*)&Bs[row * 32 + ch * 8] = *(const uint4*)&Bt[(size_t)row * ND + k0 + (i & 3) * 8];
    }
    __syncthreads();
    bf16x8 af[4], bfr[4];
    #pragma unroll
    for (int mi = 0; mi < 4; ++mi) {
      int r = wr + mi * 16 + l15;
      af[mi] = *(const bf16x8*)&As[r * 32 + (l4 ^ ((r >> 1) & 3)) * 8];
    }
    #pragma unroll
    for (int ni = 0; ni < 4; ++ni) {
      int r = wc + ni * 16 + l15;
      bfr[ni] = *(const bf16x8*)&Bs[r * 32 + (l4 ^ ((r >> 1) & 3)) * 8];
    }
    #pragma unroll
    for (int mi = 0; mi < 4; ++mi)
      #pragma unroll
      for (int ni = 0; ni < 4; ++ni)
        acc[mi][ni] = __builtin_amdgcn_mfma_f32_16x16x32_bf16(af[mi], bfr[ni],
                                                              acc[mi][ni], 0, 0, 0);
  }
  #pragma unroll
  for (int mi = 0; mi < 4; ++mi)
    #pragma unroll
    for (int ni = 0; ni < 4; ++ni) {
      int c = wc + ni * 16 + l15;
      int gc = colt * 128 + c;
      float cv = cvec[b * ND + gc];
      #pragma unroll
      for (int j = 0; j < 4; ++j) {
        int r = wr + mi * 16 + l4 * 4 + j;
        int gr = rowt * 128 + r;
        Out[(size_t)gr * ND + gc] = acc[mi][ni][j] + cv + Ysrc[(size_t)gr * ND + gc];
      }
    }
}

extern "C" void kernel_launch(void* const* d_in, const int* in_sizes, int n_in,
                              void* d_out, int out_size, void* d_ws, size_t ws_size,
                              hipStream_t stream) {
  const float* x = (const float*)d_in[0];
  const float* y = (const float*)d_in[1];
  const float* Wq = (const float*)d_in[2];
  const float* bq = (const float*)d_in[3];
  const float* Wkv = (const float*)d_in[4];
  const float* bkv = (const float*)d_in[5];
  const float* Wo = (const float*)d_in[6];
  const float* bo = (const float*)d_in[7];
  float* out = (float*)d_out;

  char* ws = (char*)d_ws;
  float* qk    = (float*)(ws + 0);          // 2*8*64*768*4  = 3,145,728
  float* attn  = (float*)(ws + 3145728);    // 8*12*64*64*4  = 1,572,864
  float* cvec  = (float*)(ws + 4718592);    // 8*768*4       = 24,576
  ushort* Wvb  = (ushort*)(ws + 4743168);   // 768*768*2     = 1,179,648
  ushort* PT   = (ushort*)(ws + 5922816);   // 8*768*768*2   = 9,437,184
  ushort* MT   = (ushort*)(ws + 15360000);  // 8*768*768*2   = 9,437,184
  // bvA (8*768*4 = 24,576 B) reuses the qk region: qk is dead after k1b,
  // and k2b1 runs strictly after k1b on the stream.
  float* bvA   = (float*)(ws + 0);

  k0_prep<<<dim3(2304), 256, 0, stream>>>(Wkv, Wvb);
  k1a_qk<<<dim3(NH, NB, 2), 512, 0, stream>>>(x, y, Wq, bq, Wkv, bkv, qk);
  k1b_attn<<<dim3(NH, NB), 256, 0, stream>>>(qk, attn);
  k2_pt<<<dim3(6, NH, NB), 256, 0, stream>>>(attn, Wo, PT);
  k2b1_bva<<<dim3(NB), 256, 0, stream>>>(attn, bkv, bvA);
  k2b2_cvec<<<dim3(6, NB), 256, 0, stream>>>(bvA, Wo, bo, cvec);
  k3_gemm<<<dim3(6, 6, NB), 256, 0, stream>>>(PT, Wvb, MT);
  k4_gemm<<<dim3(6, 16, NB), 256, 0, stream>>>(y, MT, cvec, out);
}

// Round 4
// 170.335 us; speedup vs baseline: 2.1128x; 1.0863x over previous
//
#include <hip/hip_runtime.h>
#include <hip/hip_bf16.h>

typedef __attribute__((ext_vector_type(8))) short bf16x8;
typedef __attribute__((ext_vector_type(4))) float f32x4;

#define NB 8
#define NT 2048
#define ND 768
#define NH 12
#define SCALE 0.125f
#define NKT 24  // 768/32 K-steps

__device__ __forceinline__ ushort f2b(float f) {
  __hip_bfloat16 h = __float2bfloat16(f);
  return __builtin_bit_cast(ushort, h);
}

// global -> LDS direct copy, 16B per lane; lds dst must be wave-uniform,
// HW writes lane l at lds + l*16.
#define GLDS(gp, lp)                                                        \
  __builtin_amdgcn_global_load_lds(                                         \
      (const __attribute__((address_space(1))) unsigned int*)(gp),          \
      (__attribute__((address_space(3))) unsigned int*)(lp), 16, 0, 0)

// ---------------- k0: Wv (V half of Wkv) -> bf16 ----------------
__global__ __launch_bounds__(256) void k0_prep(const float* __restrict__ Wkv,
                                               ushort* __restrict__ Wvb) {
  int i = blockIdx.x * 256 + threadIdx.x;  // over 768*768
  int c = i / ND, e = i % ND;
  Wvb[i] = f2b(Wkv[(size_t)c * 1536 + 768 + e]);
}

// ---------------- k1a: q,k projections (first 64 rows) ----------------
// qk layout: [which(0=q,1=k)][b][64][768] f32
__global__ __launch_bounds__(512) void k1a_qk(
    const float* __restrict__ x, const float* __restrict__ y,
    const float* __restrict__ Wq, const float* __restrict__ bq,
    const float* __restrict__ Wkv, const float* __restrict__ bkv,
    float* __restrict__ qk) {
  int h = blockIdx.x;
  int b = blockIdx.y;
  int which = blockIdx.z;
  const float* src = which ? y : x;
  __shared__ float sA[64][68];
  __shared__ float sB[64][68];
  int tid = threadIdx.x;
  int tx = tid & 15;   // col group (x4)
  int ty = tid >> 4;   // row group (0..31, x2)
  float acc[2][4] = {{0.f,0.f,0.f,0.f},{0.f,0.f,0.f,0.f}};
  for (int kt = 0; kt < 12; ++kt) {
    __syncthreads();
    #pragma unroll
    for (int p = 0; p < 8; ++p) {
      int i = p * 512 + tid;  // 0..4095
      int r = i >> 6, c = i & 63;
      sA[r][c] = src[(size_t)b * NT * ND + r * ND + kt * 64 + c];
      sB[r][c] = which ? Wkv[(size_t)(kt * 64 + r) * 1536 + h * 64 + c]
                       : Wq[(size_t)(kt * 64 + r) * ND + h * 64 + c];
    }
    __syncthreads();
    #pragma unroll 8
    for (int kk = 0; kk < 64; ++kk) {
      float4 bv = *(const float4*)&sB[kk][tx * 4];
      float a0 = sA[ty * 2 + 0][kk];
      float a1 = sA[ty * 2 + 1][kk];
      acc[0][0] += a0 * bv.x; acc[0][1] += a0 * bv.y;
      acc[0][2] += a0 * bv.z; acc[0][3] += a0 * bv.w;
      acc[1][0] += a1 * bv.x; acc[1][1] += a1 * bv.y;
      acc[1][2] += a1 * bv.z; acc[1][3] += a1 * bv.w;
    }
  }
  const float* bias = which ? bkv : bq;
  float* dst = qk + ((size_t)which * NB + b) * 64 * ND;
  #pragma unroll
  for (int i2 = 0; i2 < 2; ++i2)
    #pragma unroll
    for (int j = 0; j < 4; ++j)
      dst[(ty * 2 + i2) * ND + h * 64 + tx * 4 + j] =
          acc[i2][j] + bias[h * 64 + tx * 4 + j];
}

// ---------------- k1b: scores + softmax -> attn (B,12,64,64) f32 ----------------
__global__ __launch_bounds__(256) void k1b_attn(const float* __restrict__ qk,
                                                float* __restrict__ attn) {
  int h = blockIdx.x, b = blockIdx.y;
  __shared__ float qs[64][68];
  __shared__ float ks[64][68];
  __shared__ float sc[64][68];
  __shared__ float rm[64], rs[64];
  int tid = threadIdx.x;
  #pragma unroll
  for (int p = 0; p < 16; ++p) {
    int i = p * 256 + tid;
    int r = i >> 6, c = i & 63;
    qs[r][c] = qk[(size_t)b * 64 * ND + r * ND + h * 64 + c];
    ks[r][c] = qk[(size_t)(NB + b) * 64 * ND + r * ND + h * 64 + c];
  }
  __syncthreads();
  int tx = tid & 15, ty = tid >> 4;
  float a[4][4] = {};
  #pragma unroll 8
  for (int kk = 0; kk < 64; ++kk) {
    float qv[4], kv[4];
    #pragma unroll
    for (int i = 0; i < 4; ++i) qv[i] = qs[ty * 4 + i][kk];
    #pragma unroll
    for (int j = 0; j < 4; ++j) kv[j] = ks[tx * 4 + j][kk];
    #pragma unroll
    for (int i = 0; i < 4; ++i)
      #pragma unroll
      for (int j = 0; j < 4; ++j) a[i][j] += qv[i] * kv[j];
  }
  #pragma unroll
  for (int i = 0; i < 4; ++i)
    #pragma unroll
    for (int j = 0; j < 4; ++j)
      sc[ty * 4 + i][tx * 4 + j] = a[i][j] * SCALE;
  __syncthreads();
  if (tid < 64) {
    float m = -1e30f;
    for (int z = 0; z < 64; ++z) m = fmaxf(m, sc[tid][z]);
    float s = 0.f;
    for (int z = 0; z < 64; ++z) s += expf(sc[tid][z] - m);
    rm[tid] = m;
    rs[tid] = 1.0f / s;
  }
  __syncthreads();
  #pragma unroll
  for (int p = 0; p < 16; ++p) {
    int i = p * 256 + tid;
    int r = i >> 6, c = i & 63;
    attn[((size_t)(b * NH + h) * 64 + r) * 64 + c] =
        expf(sc[r][c] - rm[r]) * rs[r];
  }
}

// ---------------- k2: PT[b][j][h*64+d] = sum_s attn[b,h,d,s]*Wo[h*64+s][j] (bf16) ----------------
__global__ __launch_bounds__(256) void k2_pt(const float* __restrict__ attn,
                                             const float* __restrict__ Wo,
                                             ushort* __restrict__ PT) {
  int jt = blockIdx.x, h = blockIdx.y, b = blockIdx.z;
  __shared__ float at[64][64];
  int tid = threadIdx.x;
  #pragma unroll
  for (int p = 0; p < 16; ++p) {
    int i = p * 256 + tid;
    int d = i >> 6, s = i & 63;
    at[d][s] = attn[((size_t)(b * NH + h) * 64 + d) * 64 + s];
  }
  __syncthreads();
  int tx = tid & 31;  // j group (x4)
  int ty = tid >> 5;  // d group (x8)
  int j0 = jt * 128 + tx * 4;
  float acc[8][4] = {};
  for (int s = 0; s < 64; ++s) {
    float4 w = *(const float4*)&Wo[(size_t)(h * 64 + s) * ND + j0];
    #pragma unroll
    for (int dd = 0; dd < 8; ++dd) {
      float av = at[ty * 8 + dd][s];
      acc[dd][0] += av * w.x; acc[dd][1] += av * w.y;
      acc[dd][2] += av * w.z; acc[dd][3] += av * w.w;
    }
  }
  #pragma unroll
  for (int jj = 0; jj < 4; ++jj) {
    ushort tmp[8];
    #pragma unroll
    for (int dd = 0; dd < 8; ++dd) tmp[dd] = f2b(acc[dd][jj]);
    *(uint4*)&PT[(size_t)b * ND * ND + (size_t)(j0 + jj) * ND + h * 64 + ty * 8] =
        *(const uint4*)tmp;
  }
}

// ---------------- k2b1: bvA[b][h*64+s] = sum_d bv[h*64+d]*attn[b,h,d,s] ----------------
__global__ __launch_bounds__(256) void k2b1_bva(const float* __restrict__ attn,
                                                const float* __restrict__ bkv,
                                                float* __restrict__ bvA) {
  int b = blockIdx.x;
  int tid = threadIdx.x;
  for (int i = tid; i < ND; i += 256) {
    int h = i >> 6, s = i & 63;
    const float* at = attn + (size_t)(b * NH + h) * 64 * 64;
    float acc = 0.f;
    #pragma unroll 8
    for (int d = 0; d < 64; ++d) acc += bkv[768 + h * 64 + d] * at[d * 64 + s];
    bvA[b * ND + i] = acc;
  }
}

// ---------------- k2b2: cvec[b][j] = sum_e bvA[b][e]*Wo[e][j] + bo[j] ----------------
__global__ __launch_bounds__(256) void k2b2_cvec(const float* __restrict__ bvA,
                                                 const float* __restrict__ Wo,
                                                 const float* __restrict__ bo,
                                                 float* __restrict__ cvec) {
  int jt = blockIdx.x, b = blockIdx.y;
  int tid = threadIdx.x;
  __shared__ float bl[768];
  __shared__ f32x4 red[256];
  for (int i = tid; i < ND; i += 256) bl[i] = bvA[b * ND + i];
  __syncthreads();
  int jq = tid & 31;   // j quad
  int es = tid >> 5;   // e split 0..7
  int j0 = jt * 128 + jq * 4;
  f32x4 acc = {0.f, 0.f, 0.f, 0.f};
  #pragma unroll 8
  for (int e = es * 96; e < es * 96 + 96; ++e) {
    float4 w = *(const float4*)&Wo[(size_t)e * ND + j0];
    float bv = bl[e];
    acc[0] += bv * w.x; acc[1] += bv * w.y;
    acc[2] += bv * w.z; acc[3] += bv * w.w;
  }
  red[tid] = acc;
  __syncthreads();
  if (tid < 32) {
    f32x4 s = red[tid];
    #pragma unroll
    for (int k = 1; k < 8; ++k) {
      f32x4 r = red[tid + 32 * k];
      s[0] += r[0]; s[1] += r[1]; s[2] += r[2]; s[3] += r[3];
    }
    #pragma unroll
    for (int c = 0; c < 4; ++c)
      cvec[b * ND + j0 + c] = s[c] + bo[j0 + c];
  }
}

// ---------------- k3: MT[b][j][c] = sum_e PT[b][j][e]*Wvb[c][e] + (j==c) ----------------
// Double-buffered global_load_lds pipeline, 1 barrier / K-step.
__global__ __launch_bounds__(256, 3) void k3_gemm(const ushort* __restrict__ PT,
                                                  const ushort* __restrict__ Wvb,
                                                  ushort* __restrict__ MT) {
  int b = blockIdx.z, rowt = blockIdx.y, colt = blockIdx.x;
  const ushort* Ag = PT + (size_t)b * ND * ND + (size_t)rowt * 128 * ND;
  const ushort* Bg = Wvb + (size_t)colt * 128 * ND;
  ushort* Cout = MT + (size_t)b * ND * ND + (size_t)rowt * 128 * ND + colt * 128;

  __shared__ ushort As[2][128 * 32];
  __shared__ ushort Bs[2][128 * 32];
  int tid = threadIdx.x, w = tid >> 6, lane = tid & 63;
  int wr = (w >> 1) * 64, wc = (w & 1) * 64;
  int l15 = lane & 15, l4 = lane >> 4;
  int r0 = lane >> 2, cl = (lane & 3) * 8;  // staging: 4 lanes/row, 8 ushorts each

  f32x4 acc[4][4];
  #pragma unroll
  for (int mi = 0; mi < 4; ++mi)
    #pragma unroll
    for (int ni = 0; ni < 4; ++ni) acc[mi][ni] = {0.f, 0.f, 0.f, 0.f};

  auto STAGE = [&](int bufi, int kk) {
    #pragma unroll
    for (int cc = 0; cc < 2; ++cc) {
      int c = w + cc * 4;          // wave-uniform chunk id 0..7
      int row = c * 16 + r0;
      GLDS(&Ag[(size_t)row * ND + kk + cl], &As[bufi][c * 512]);
      GLDS(&Bg[(size_t)row * ND + kk + cl], &Bs[bufi][c * 512]);
    }
  };

  STAGE(0, 0);
  __syncthreads();
  int cur = 0;
  for (int t = 0; t < NKT; ++t) {
    if (t + 1 < NKT) STAGE(cur ^ 1, (t + 1) * 32);
    bf16x8 af[4], bfr[4];
    #pragma unroll
    for (int mi = 0; mi < 4; ++mi)
      af[mi] = *(const bf16x8*)&As[cur][(wr + mi * 16 + l15) * 32 + l4 * 8];
    #pragma unroll
    for (int ni = 0; ni < 4; ++ni)
      bfr[ni] = *(const bf16x8*)&Bs[cur][(wc + ni * 16 + l15) * 32 + l4 * 8];
    #pragma unroll
    for (int mi = 0; mi < 4; ++mi)
      #pragma unroll
      for (int ni = 0; ni < 4; ++ni)
        acc[mi][ni] = __builtin_amdgcn_mfma_f32_16x16x32_bf16(af[mi], bfr[ni],
                                                              acc[mi][ni], 0, 0, 0);
    __syncthreads();
    cur ^= 1;
  }
  bool diagt = (rowt == colt);
  #pragma unroll
  for (int mi = 0; mi < 4; ++mi)
    #pragma unroll
    for (int ni = 0; ni < 4; ++ni)
      #pragma unroll
      for (int j = 0; j < 4; ++j) {
        int r = wr + mi * 16 + l4 * 4 + j;
        int c = wc + ni * 16 + l15;
        float v = acc[mi][ni][j] + ((diagt && r == c) ? 1.0f : 0.0f);
        Cout[(size_t)r * ND + c] = f2b(v);
      }
}

// ---------------- k4: out[b] = y[b] @ (M_b + I) + cvec[b] ----------------
// A: f32 y, reg-staged issue-early/convert-late; B: bf16 MT via global_load_lds.
__global__ __launch_bounds__(256, 3) void k4_gemm(const float* __restrict__ y,
                                                  const ushort* __restrict__ MT,
                                                  const float* __restrict__ cvec,
                                                  float* __restrict__ out) {
  int b = blockIdx.z, rowt = blockIdx.y, colt = blockIdx.x;
  const float* Ag = y + (size_t)b * NT * ND + (size_t)rowt * 128 * ND;
  const ushort* Bg = MT + (size_t)b * ND * ND + (size_t)colt * 128 * ND;
  float* Out = out + (size_t)b * NT * ND;

  __shared__ ushort As[2][128 * 32];
  __shared__ ushort Bs[2][128 * 32];
  int tid = threadIdx.x, w = tid >> 6, lane = tid & 63;
  int wr = (w >> 1) * 64, wc = (w & 1) * 64;
  int l15 = lane & 15, l4 = lane >> 4;
  int r0 = lane >> 2, cl = (lane & 3) * 8;
  int ar = tid >> 1;            // A staging row (2 threads/row)
  int ag0 = (tid & 1) * 2;      // A staging granule base (0 or 2)

  f32x4 acc[4][4];
  #pragma unroll
  for (int mi = 0; mi < 4; ++mi)
    #pragma unroll
    for (int ni = 0; ni < 4; ++ni) acc[mi][ni] = {0.f, 0.f, 0.f, 0.f};

  float4 ra[4];
  auto AISSUE = [&](int kk) {
    #pragma unroll
    for (int q = 0; q < 4; ++q)
      ra[q] = *(const float4*)&Ag[(size_t)ar * ND + kk + ag0 * 8 + q * 4];
  };
  auto AWRITE = [&](int bufi) {
    ushort u[16];
    #pragma unroll
    for (int q = 0; q < 4; ++q) {
      u[q * 4 + 0] = f2b(ra[q].x); u[q * 4 + 1] = f2b(ra[q].y);
      u[q * 4 + 2] = f2b(ra[q].z); u[q * 4 + 3] = f2b(ra[q].w);
    }
    int g0 = (ag0 + (ar >> 1)) & 3;        // bank-floor granule swizzle
    int g1 = (ag0 + 1 + (ar >> 1)) & 3;
    *(uint4*)&As[bufi][ar * 32 + g0 * 8] = *(const uint4*)&u[0];
    *(uint4*)&As[bufi][ar * 32 + g1 * 8] = *(const uint4*)&u[8];
  };
  auto BSTAGE = [&](int bufi, int kk) {
    #pragma unroll
    for (int cc = 0; cc < 2; ++cc) {
      int c = w + cc * 4;
      GLDS(&Bg[(size_t)(c * 16 + r0) * ND + kk + cl], &Bs[bufi][c * 512]);
    }
  };

  AISSUE(0);
  BSTAGE(0, 0);
  AWRITE(0);
  __syncthreads();
  int cur = 0;
  for (int t = 0; t < NKT; ++t) {
    bool more = (t + 1 < NKT);
    if (more) { AISSUE((t + 1) * 32); BSTAGE(cur ^ 1, (t + 1) * 32); }
    bf16x8 af[4], bfr[4];
    #pragma unroll
    for (int mi = 0; mi < 4; ++mi) {
      int r = wr + mi * 16 + l15;
      int g = (l4 + (r >> 1)) & 3;         // match AWRITE swizzle
      af[mi] = *(const bf16x8*)&As[cur][r * 32 + g * 8];
    }
    #pragma unroll
    for (int ni = 0; ni < 4; ++ni)
      bfr[ni] = *(const bf16x8*)&Bs[cur][(wc + ni * 16 + l15) * 32 + l4 * 8];
    #pragma unroll
    for (int mi = 0; mi < 4; ++mi)
      #pragma unroll
      for (int ni = 0; ni < 4; ++ni)
        acc[mi][ni] = __builtin_amdgcn_mfma_f32_16x16x32_bf16(af[mi], bfr[ni],
                                                              acc[mi][ni], 0, 0, 0);
    if (more) AWRITE(cur ^ 1);
    __syncthreads();
    cur ^= 1;
  }
  #pragma unroll
  for (int mi = 0; mi < 4; ++mi)
    #pragma unroll
    for (int ni = 0; ni < 4; ++ni) {
      int gc = colt * 128 + wc + ni * 16 + l15;
      float cv = cvec[b * ND + gc];
      #pragma unroll
      for (int j = 0; j < 4; ++j) {
        int gr = rowt * 128 + wr + mi * 16 + l4 * 4 + j;
        Out[(size_t)gr * ND + gc] = acc[mi][ni][j] + cv;
      }
    }
}

extern "C" void kernel_launch(void* const* d_in, const int* in_sizes, int n_in,
                              void* d_out, int out_size, void* d_ws, size_t ws_size,
                              hipStream_t stream) {
  const float* x = (const float*)d_in[0];
  const float* y = (const float*)d_in[1];
  const float* Wq = (const float*)d_in[2];
  const float* bq = (const float*)d_in[3];
  const float* Wkv = (const float*)d_in[4];
  const float* bkv = (const float*)d_in[5];
  const float* Wo = (const float*)d_in[6];
  const float* bo = (const float*)d_in[7];
  float* out = (float*)d_out;

  char* ws = (char*)d_ws;
  float* qk    = (float*)(ws + 0);          // 2*8*64*768*4  = 3,145,728
  float* attn  = (float*)(ws + 3145728);    // 8*12*64*64*4  = 1,572,864
  float* cvec  = (float*)(ws + 4718592);    // 8*768*4       = 24,576
  ushort* Wvb  = (ushort*)(ws + 4743168);   // 768*768*2     = 1,179,648
  ushort* PT   = (ushort*)(ws + 5922816);   // 8*768*768*2   = 9,437,184
  ushort* MT   = (ushort*)(ws + 15360000);  // 8*768*768*2   = 9,437,184
  float* bvA   = (float*)(ws + 0);          // reuses dead qk region after k1b

  k0_prep<<<dim3(2304), 256, 0, stream>>>(Wkv, Wvb);
  k1a_qk<<<dim3(NH, NB, 2), 512, 0, stream>>>(x, y, Wq, bq, Wkv, bkv, qk);
  k1b_attn<<<dim3(NH, NB), 256, 0, stream>>>(qk, attn);
  k2_pt<<<dim3(6, NH, NB), 256, 0, stream>>>(attn, Wo, PT);
  k2b1_bva<<<dim3(NB), 256, 0, stream>>>(attn, bkv, bvA);
  k2b2_cvec<<<dim3(6, NB), 256, 0, stream>>>(bvA, Wo, bo, cvec);
  k3_gemm<<<dim3(6, 6, NB), 256, 0, stream>>>(PT, Wvb, MT);
  k4_gemm<<<dim3(6, 16, NB), 256, 0, stream>>>(y, MT, cvec, out);
}

// Round 5
// 167.715 us; speedup vs baseline: 2.1458x; 1.0156x over previous
//
#include <hip/hip_runtime.h>
#include <hip/hip_bf16.h>

typedef __attribute__((ext_vector_type(8))) short bf16x8;
typedef __attribute__((ext_vector_type(4))) float f32x4;

#define NB 8
#define NT 2048
#define ND 768
#define NH 12
#define SCALE 0.125f
#define NKT 24  // 768/32 K-steps

__device__ __forceinline__ ushort f2b(float f) {
  __hip_bfloat16 h = __float2bfloat16(f);
  return __builtin_bit_cast(ushort, h);
}

// global -> LDS direct copy, 16B per lane; lds dst wave-uniform,
// HW writes lane l at lds + l*16.
#define GLDS(gp, lp)                                                        \
  __builtin_amdgcn_global_load_lds(                                         \
      (const __attribute__((address_space(1))) unsigned int*)(gp),          \
      (__attribute__((address_space(3))) unsigned int*)(lp), 16, 0, 0)

// ---------------- k0: Wv (V half of Wkv) -> bf16 ----------------
__global__ __launch_bounds__(256) void k0_prep(const float* __restrict__ Wkv,
                                               ushort* __restrict__ Wvb) {
  int i = blockIdx.x * 256 + threadIdx.x;  // over 768*768
  int c = i / ND, e = i % ND;
  Wvb[i] = f2b(Wkv[(size_t)c * 1536 + 768 + e]);
}

// ---------------- k1a: q,k projections (first 64 rows) ----------------
// qk layout: [which(0=q,1=k)][b][64][768] f32
__global__ __launch_bounds__(512) void k1a_qk(
    const float* __restrict__ x, const float* __restrict__ y,
    const float* __restrict__ Wq, const float* __restrict__ bq,
    const float* __restrict__ Wkv, const float* __restrict__ bkv,
    float* __restrict__ qk) {
  int h = blockIdx.x;
  int b = blockIdx.y;
  int which = blockIdx.z;
  const float* src = which ? y : x;
  __shared__ float sA[64][68];
  __shared__ float sB[64][68];
  int tid = threadIdx.x;
  int tx = tid & 15;   // col group (x4)
  int ty = tid >> 4;   // row group (0..31, x2)
  float acc[2][4] = {{0.f,0.f,0.f,0.f},{0.f,0.f,0.f,0.f}};
  for (int kt = 0; kt < 12; ++kt) {
    __syncthreads();
    #pragma unroll
    for (int p = 0; p < 8; ++p) {
      int i = p * 512 + tid;  // 0..4095
      int r = i >> 6, c = i & 63;
      sA[r][c] = src[(size_t)b * NT * ND + r * ND + kt * 64 + c];
      sB[r][c] = which ? Wkv[(size_t)(kt * 64 + r) * 1536 + h * 64 + c]
                       : Wq[(size_t)(kt * 64 + r) * ND + h * 64 + c];
    }
    __syncthreads();
    #pragma unroll 8
    for (int kk = 0; kk < 64; ++kk) {
      float4 bv = *(const float4*)&sB[kk][tx * 4];
      float a0 = sA[ty * 2 + 0][kk];
      float a1 = sA[ty * 2 + 1][kk];
      acc[0][0] += a0 * bv.x; acc[0][1] += a0 * bv.y;
      acc[0][2] += a0 * bv.z; acc[0][3] += a0 * bv.w;
      acc[1][0] += a1 * bv.x; acc[1][1] += a1 * bv.y;
      acc[1][2] += a1 * bv.z; acc[1][3] += a1 * bv.w;
    }
  }
  const float* bias = which ? bkv : bq;
  float* dst = qk + ((size_t)which * NB + b) * 64 * ND;
  #pragma unroll
  for (int i2 = 0; i2 < 2; ++i2)
    #pragma unroll
    for (int j = 0; j < 4; ++j)
      dst[(ty * 2 + i2) * ND + h * 64 + tx * 4 + j] =
          acc[i2][j] + bias[h * 64 + tx * 4 + j];
}

// ---------------- k1b: scores + softmax -> attn (B,12,64,64) f32 ----------------
__global__ __launch_bounds__(256) void k1b_attn(const float* __restrict__ qk,
                                                float* __restrict__ attn) {
  int h = blockIdx.x, b = blockIdx.y;
  __shared__ float qs[64][68];
  __shared__ float ks[64][68];
  __shared__ float sc[64][68];
  __shared__ float rm[64], rs[64];
  int tid = threadIdx.x;
  #pragma unroll
  for (int p = 0; p < 16; ++p) {
    int i = p * 256 + tid;
    int r = i >> 6, c = i & 63;
    qs[r][c] = qk[(size_t)b * 64 * ND + r * ND + h * 64 + c];
    ks[r][c] = qk[(size_t)(NB + b) * 64 * ND + r * ND + h * 64 + c];
  }
  __syncthreads();
  int tx = tid & 15, ty = tid >> 4;
  float a[4][4] = {};
  #pragma unroll 8
  for (int kk = 0; kk < 64; ++kk) {
    float qv[4], kv[4];
    #pragma unroll
    for (int i = 0; i < 4; ++i) qv[i] = qs[ty * 4 + i][kk];
    #pragma unroll
    for (int j = 0; j < 4; ++j) kv[j] = ks[tx * 4 + j][kk];
    #pragma unroll
    for (int i = 0; i < 4; ++i)
      #pragma unroll
      for (int j = 0; j < 4; ++j) a[i][j] += qv[i] * kv[j];
  }
  #pragma unroll
  for (int i = 0; i < 4; ++i)
    #pragma unroll
    for (int j = 0; j < 4; ++j)
      sc[ty * 4 + i][tx * 4 + j] = a[i][j] * SCALE;
  __syncthreads();
  if (tid < 64) {
    float m = -1e30f;
    for (int z = 0; z < 64; ++z) m = fmaxf(m, sc[tid][z]);
    float s = 0.f;
    for (int z = 0; z < 64; ++z) s += expf(sc[tid][z] - m);
    rm[tid] = m;
    rs[tid] = 1.0f / s;
  }
  __syncthreads();
  #pragma unroll
  for (int p = 0; p < 16; ++p) {
    int i = p * 256 + tid;
    int r = i >> 6, c = i & 63;
    attn[((size_t)(b * NH + h) * 64 + r) * 64 + c] =
        expf(sc[r][c] - rm[r]) * rs[r];
  }
}

// ---------------- k2: PT[b][j][h*64+d] = sum_s attn[b,h,d,s]*Wo[h*64+s][j] (bf16) ----------------
__global__ __launch_bounds__(256) void k2_pt(const float* __restrict__ attn,
                                             const float* __restrict__ Wo,
                                             ushort* __restrict__ PT) {
  int jt = blockIdx.x, h = blockIdx.y, b = blockIdx.z;
  __shared__ float at[64][64];
  int tid = threadIdx.x;
  #pragma unroll
  for (int p = 0; p < 16; ++p) {
    int i = p * 256 + tid;
    int d = i >> 6, s = i & 63;
    at[d][s] = attn[((size_t)(b * NH + h) * 64 + d) * 64 + s];
  }
  __syncthreads();
  int tx = tid & 31;  // j group (x4)
  int ty = tid >> 5;  // d group (x8)
  int j0 = jt * 128 + tx * 4;
  float acc[8][4] = {};
  for (int s = 0; s < 64; ++s) {
    float4 w = *(const float4*)&Wo[(size_t)(h * 64 + s) * ND + j0];
    #pragma unroll
    for (int dd = 0; dd < 8; ++dd) {
      float av = at[ty * 8 + dd][s];
      acc[dd][0] += av * w.x; acc[dd][1] += av * w.y;
      acc[dd][2] += av * w.z; acc[dd][3] += av * w.w;
    }
  }
  #pragma unroll
  for (int jj = 0; jj < 4; ++jj) {
    ushort tmp[8];
    #pragma unroll
    for (int dd = 0; dd < 8; ++dd) tmp[dd] = f2b(acc[dd][jj]);
    *(uint4*)&PT[(size_t)b * ND * ND + (size_t)(j0 + jj) * ND + h * 64 + ty * 8] =
        *(const uint4*)tmp;
  }
}

// ---------------- k2b1: bvA[b][h*64+s] = sum_d bv[h*64+d]*attn[b,h,d,s] ----------------
__global__ __launch_bounds__(256) void k2b1_bva(const float* __restrict__ attn,
                                                const float* __restrict__ bkv,
                                                float* __restrict__ bvA) {
  int b = blockIdx.x;
  int tid = threadIdx.x;
  for (int i = tid; i < ND; i += 256) {
    int h = i >> 6, s = i & 63;
    const float* at = attn + (size_t)(b * NH + h) * 64 * 64;
    float acc = 0.f;
    #pragma unroll 8
    for (int d = 0; d < 64; ++d) acc += bkv[768 + h * 64 + d] * at[d * 64 + s];
    bvA[b * ND + i] = acc;
  }
}

// ---------------- k2b2: cvec[b][j] = sum_e bvA[b][e]*Wo[e][j] + bo[j] ----------------
__global__ __launch_bounds__(256) void k2b2_cvec(const float* __restrict__ bvA,
                                                 const float* __restrict__ Wo,
                                                 const float* __restrict__ bo,
                                                 float* __restrict__ cvec) {
  int jt = blockIdx.x, b = blockIdx.y;
  int tid = threadIdx.x;
  __shared__ float bl[768];
  __shared__ f32x4 red[256];
  for (int i = tid; i < ND; i += 256) bl[i] = bvA[b * ND + i];
  __syncthreads();
  int jq = tid & 31;   // j quad
  int es = tid >> 5;   // e split 0..7
  int j0 = jt * 128 + jq * 4;
  f32x4 acc = {0.f, 0.f, 0.f, 0.f};
  #pragma unroll 8
  for (int e = es * 96; e < es * 96 + 96; ++e) {
    float4 w = *(const float4*)&Wo[(size_t)e * ND + j0];
    float bv = bl[e];
    acc[0] += bv * w.x; acc[1] += bv * w.y;
    acc[2] += bv * w.z; acc[3] += bv * w.w;
  }
  red[tid] = acc;
  __syncthreads();
  if (tid < 32) {
    f32x4 s = red[tid];
    #pragma unroll
    for (int k = 1; k < 8; ++k) {
      f32x4 r = red[tid + 32 * k];
      s[0] += r[0]; s[1] += r[1]; s[2] += r[2]; s[3] += r[3];
    }
    #pragma unroll
    for (int c = 0; c < 4; ++c)
      cvec[b * ND + j0 + c] = s[c] + bo[j0 + c];
  }
}

// ---------------- k3: MT[b][j][c] = sum_e PT[b][j][e]*Wvb[c][e] + (j==c) ----------------
// dbuf GLDS pipeline; LDS chunk swizzle via pre-swizzled GLOBAL source
// (GLDS dest must stay linear), chunk' = q ^ ((row>>1)&3); read with same XOR.
__global__ __launch_bounds__(256, 3) void k3_gemm(const ushort* __restrict__ PT,
                                                  const ushort* __restrict__ Wvb,
                                                  ushort* __restrict__ MT) {
  int b = blockIdx.z, rowt = blockIdx.y, colt = blockIdx.x;
  const ushort* Ag = PT + (size_t)b * ND * ND + (size_t)rowt * 128 * ND;
  const ushort* Bg = Wvb + (size_t)colt * 128 * ND;
  ushort* Cout = MT + (size_t)b * ND * ND + (size_t)rowt * 128 * ND + colt * 128;

  __shared__ ushort As[2][128 * 32];
  __shared__ ushort Bs[2][128 * 32];
  int tid = threadIdx.x, w = tid >> 6, lane = tid & 63;
  int wr = (w >> 1) * 64, wc = (w & 1) * 64;
  int l15 = lane & 15, l4 = lane >> 4;
  int r0 = lane >> 2, q = lane & 3;  // staging: 4 lanes/row, 16B each

  f32x4 acc[4][4];
  #pragma unroll
  for (int mi = 0; mi < 4; ++mi)
    #pragma unroll
    for (int ni = 0; ni < 4; ++ni) acc[mi][ni] = {0.f, 0.f, 0.f, 0.f};

  auto STAGE = [&](int bufi, int kk) {
    #pragma unroll
    for (int cc = 0; cc < 2; ++cc) {
      int c = w + cc * 4;          // wave-uniform chunk id 0..7
      int row = c * 16 + r0;
      int sq = (q ^ ((row >> 1) & 3)) * 8;  // pre-swizzled source chunk
      GLDS(&Ag[(size_t)row * ND + kk + sq], &As[bufi][c * 512]);
      GLDS(&Bg[(size_t)row * ND + kk + sq], &Bs[bufi][c * 512]);
    }
  };

  STAGE(0, 0);
  __syncthreads();
  int cur = 0;
  for (int t = 0; t < NKT; ++t) {
    if (t + 1 < NKT) STAGE(cur ^ 1, (t + 1) * 32);
    bf16x8 af[4], bfr[4];
    #pragma unroll
    for (int mi = 0; mi < 4; ++mi) {
      int r = wr + mi * 16 + l15;
      af[mi] = *(const bf16x8*)&As[cur][r * 32 + (l4 ^ ((r >> 1) & 3)) * 8];
    }
    #pragma unroll
    for (int ni = 0; ni < 4; ++ni) {
      int r = wc + ni * 16 + l15;
      bfr[ni] = *(const bf16x8*)&Bs[cur][r * 32 + (l4 ^ ((r >> 1) & 3)) * 8];
    }
    #pragma unroll
    for (int mi = 0; mi < 4; ++mi)
      #pragma unroll
      for (int ni = 0; ni < 4; ++ni)
        acc[mi][ni] = __builtin_amdgcn_mfma_f32_16x16x32_bf16(af[mi], bfr[ni],
                                                              acc[mi][ni], 0, 0, 0);
    __syncthreads();
    cur ^= 1;
  }
  bool diagt = (rowt == colt);
  #pragma unroll
  for (int mi = 0; mi < 4; ++mi)
    #pragma unroll
    for (int ni = 0; ni < 4; ++ni)
      #pragma unroll
      for (int j = 0; j < 4; ++j) {
        int r = wr + mi * 16 + l4 * 4 + j;
        int c = wc + ni * 16 + l15;
        float v = acc[mi][ni][j] + ((diagt && r == c) ? 1.0f : 0.0f);
        Cout[(size_t)r * ND + c] = f2b(v);
      }
}

// ---------------- k4: out[b] = y[b] @ (M_b + I) + cvec[b] ----------------
// 128x64 tiles, 1536 blocks (6/CU), XCD-chunked swizzle (XCD x <- batch x).
// A: f32 y reg-staged (issue-early/write-late, rotation swizzle);
// B: GLDS with pre-swizzled source.
__global__ __launch_bounds__(256, 5) void k4_gemm(const float* __restrict__ y,
                                                  const ushort* __restrict__ MT,
                                                  const float* __restrict__ cvec,
                                                  float* __restrict__ out) {
  int flat = blockIdx.x;                  // 0..1535
  int work = (flat & 7) * 192 + (flat >> 3);  // chunked XCD swizzle (1536%8==0)
  int b = work / 192;
  int rem = work % 192;
  int rowt = rem / 12;   // 16 row tiles of 128
  int colt = rem % 12;   // 12 col tiles of 64
  const float* Ag = y + (size_t)b * NT * ND + (size_t)rowt * 128 * ND;
  const ushort* Bg = MT + (size_t)b * ND * ND + (size_t)colt * 64 * ND;
  float* Out = out + (size_t)b * NT * ND;

  __shared__ ushort As[2][128 * 32];  // 8 KiB each
  __shared__ ushort Bs[2][64 * 32];   // 4 KiB each
  int tid = threadIdx.x, w = tid >> 6, lane = tid & 63;
  int wr = (w >> 1) * 64, wc = (w & 1) * 32;
  int l15 = lane & 15, l4 = lane >> 4;
  int r0 = lane >> 2, q = lane & 3;
  int ar = tid >> 1;            // A staging row (2 threads/row)
  int ag0 = (tid & 1) * 2;      // A staging granule base (0 or 2)

  f32x4 acc[4][2];
  #pragma unroll
  for (int mi = 0; mi < 4; ++mi)
    #pragma unroll
    for (int ni = 0; ni < 2; ++ni) acc[mi][ni] = {0.f, 0.f, 0.f, 0.f};

  float4 ra[4];
  auto AISSUE = [&](int kk) {
    #pragma unroll
    for (int p = 0; p < 4; ++p)
      ra[p] = *(const float4*)&Ag[(size_t)ar * ND + kk + ag0 * 8 + p * 4];
  };
  auto AWRITE = [&](int bufi) {
    ushort u[16];
    #pragma unroll
    for (int p = 0; p < 4; ++p) {
      u[p * 4 + 0] = f2b(ra[p].x); u[p * 4 + 1] = f2b(ra[p].y);
      u[p * 4 + 2] = f2b(ra[p].z); u[p * 4 + 3] = f2b(ra[p].w);
    }
    int g0 = (ag0 + (ar >> 1)) & 3;        // rotation granule swizzle
    int g1 = (ag0 + 1 + (ar >> 1)) & 3;
    *(uint4*)&As[bufi][ar * 32 + g0 * 8] = *(const uint4*)&u[0];
    *(uint4*)&As[bufi][ar * 32 + g1 * 8] = *(const uint4*)&u[8];
  };
  auto BSTAGE = [&](int bufi, int kk) {
    int row = w * 16 + r0;                 // 64 rows, chunk id = w
    int sq = (q ^ ((row >> 1) & 3)) * 8;   // pre-swizzled source chunk
    GLDS(&Bg[(size_t)row * ND + kk + sq], &Bs[bufi][w * 512]);
  };

  AISSUE(0);
  BSTAGE(0, 0);
  AWRITE(0);
  __syncthreads();
  int cur = 0;
  for (int t = 0; t < NKT; ++t) {
    bool more = (t + 1 < NKT);
    if (more) { AISSUE((t + 1) * 32); BSTAGE(cur ^ 1, (t + 1) * 32); }
    bf16x8 af[4], bfr[2];
    #pragma unroll
    for (int mi = 0; mi < 4; ++mi) {
      int r = wr + mi * 16 + l15;
      int g = (l4 + (r >> 1)) & 3;         // match AWRITE swizzle
      af[mi] = *(const bf16x8*)&As[cur][r * 32 + g * 8];
    }
    #pragma unroll
    for (int ni = 0; ni < 2; ++ni) {
      int r = wc + ni * 16 + l15;
      bfr[ni] = *(const bf16x8*)&Bs[cur][r * 32 + (l4 ^ ((r >> 1) & 3)) * 8];
    }
    #pragma unroll
    for (int mi = 0; mi < 4; ++mi)
      #pragma unroll
      for (int ni = 0; ni < 2; ++ni)
        acc[mi][ni] = __builtin_amdgcn_mfma_f32_16x16x32_bf16(af[mi], bfr[ni],
                                                              acc[mi][ni], 0, 0, 0);
    if (more) AWRITE(cur ^ 1);
    __syncthreads();
    cur ^= 1;
  }
  #pragma unroll
  for (int mi = 0; mi < 4; ++mi)
    #pragma unroll
    for (int ni = 0; ni < 2; ++ni) {
      int gc = colt * 64 + wc + ni * 16 + l15;
      float cv = cvec[b * ND + gc];
      #pragma unroll
      for (int j = 0; j < 4; ++j) {
        int gr = rowt * 128 + wr + mi * 16 + l4 * 4 + j;
        Out[(size_t)gr * ND + gc] = acc[mi][ni][j] + cv;
      }
    }
}

extern "C" void kernel_launch(void* const* d_in, const int* in_sizes, int n_in,
                              void* d_out, int out_size, void* d_ws, size_t ws_size,
                              hipStream_t stream) {
  const float* x = (const float*)d_in[0];
  const float* y = (const float*)d_in[1];
  const float* Wq = (const float*)d_in[2];
  const float* bq = (const float*)d_in[3];
  const float* Wkv = (const float*)d_in[4];
  const float* bkv = (const float*)d_in[5];
  const float* Wo = (const float*)d_in[6];
  const float* bo = (const float*)d_in[7];
  float* out = (float*)d_out;

  char* ws = (char*)d_ws;
  float* qk    = (float*)(ws + 0);          // 2*8*64*768*4  = 3,145,728
  float* attn  = (float*)(ws + 3145728);    // 8*12*64*64*4  = 1,572,864
  float* cvec  = (float*)(ws + 4718592);    // 8*768*4       = 24,576
  ushort* Wvb  = (ushort*)(ws + 4743168);   // 768*768*2     = 1,179,648
  ushort* PT   = (ushort*)(ws + 5922816);   // 8*768*768*2   = 9,437,184
  ushort* MT   = (ushort*)(ws + 15360000);  // 8*768*768*2   = 9,437,184
  float* bvA   = (float*)(ws + 0);          // reuses dead qk region after k1b

  k0_prep<<<dim3(2304), 256, 0, stream>>>(Wkv, Wvb);
  k1a_qk<<<dim3(NH, NB, 2), 512, 0, stream>>>(x, y, Wq, bq, Wkv, bkv, qk);
  k1b_attn<<<dim3(NH, NB), 256, 0, stream>>>(qk, attn);
  k2_pt<<<dim3(6, NH, NB), 256, 0, stream>>>(attn, Wo, PT);
  k2b1_bva<<<dim3(NB), 256, 0, stream>>>(attn, bkv, bvA);
  k2b2_cvec<<<dim3(6, NB), 256, 0, stream>>>(bvA, Wo, bo, cvec);
  k3_gemm<<<dim3(6, 6, NB), 256, 0, stream>>>(PT, Wvb, MT);
  k4_gemm<<<dim3(1536), 256, 0, stream>>>(y, MT, cvec, out);
}

// Round 6
// 148.779 us; speedup vs baseline: 2.4189x; 1.1273x over previous
//
#include <hip/hip_runtime.h>
#include <hip/hip_bf16.h>

typedef __attribute__((ext_vector_type(8))) short bf16x8;
typedef __attribute__((ext_vector_type(4))) float f32x4;

#define NB 8
#define NT 2048
#define ND 768
#define NH 12
#define SCALE 0.125f
#define NKT 24  // 768/32 K-steps

__device__ __forceinline__ ushort f2b(float f) {
  __hip_bfloat16 h = __float2bfloat16(f);
  return __builtin_bit_cast(ushort, h);
}

// global -> LDS direct copy, 16B per lane; lds dst wave-uniform,
// HW writes lane l at lds + l*16.
#define GLDS(gp, lp)                                                        \
  __builtin_amdgcn_global_load_lds(                                         \
      (const __attribute__((address_space(1))) unsigned int*)(gp),          \
      (__attribute__((address_space(3))) unsigned int*)(lp), 16, 0, 0)

// ---------------- k0: Wv (V half of Wkv) -> bf16 ----------------
__global__ __launch_bounds__(256) void k0_prep(const float* __restrict__ Wkv,
                                               ushort* __restrict__ Wvb) {
  int i = blockIdx.x * 256 + threadIdx.x;  // over 768*768
  int c = i / ND, e = i % ND;
  Wvb[i] = f2b(Wkv[(size_t)c * 1536 + 768 + e]);
}

// ---------------- k1a: q,k projections (first 64 rows) ----------------
// qk layout: [which(0=q,1=k)][b][64][768] f32
__global__ __launch_bounds__(512) void k1a_qk(
    const float* __restrict__ x, const float* __restrict__ y,
    const float* __restrict__ Wq, const float* __restrict__ bq,
    const float* __restrict__ Wkv, const float* __restrict__ bkv,
    float* __restrict__ qk) {
  int h = blockIdx.x;
  int b = blockIdx.y;
  int which = blockIdx.z;
  const float* src = which ? y : x;
  __shared__ float sA[64][68];
  __shared__ float sB[64][68];
  int tid = threadIdx.x;
  int tx = tid & 15;   // col group (x4)
  int ty = tid >> 4;   // row group (0..31, x2)
  float acc[2][4] = {{0.f,0.f,0.f,0.f},{0.f,0.f,0.f,0.f}};
  for (int kt = 0; kt < 12; ++kt) {
    __syncthreads();
    #pragma unroll
    for (int p = 0; p < 8; ++p) {
      int i = p * 512 + tid;  // 0..4095
      int r = i >> 6, c = i & 63;
      sA[r][c] = src[(size_t)b * NT * ND + r * ND + kt * 64 + c];
      sB[r][c] = which ? Wkv[(size_t)(kt * 64 + r) * 1536 + h * 64 + c]
                       : Wq[(size_t)(kt * 64 + r) * ND + h * 64 + c];
    }
    __syncthreads();
    #pragma unroll 8
    for (int kk = 0; kk < 64; ++kk) {
      float4 bv = *(const float4*)&sB[kk][tx * 4];
      float a0 = sA[ty * 2 + 0][kk];
      float a1 = sA[ty * 2 + 1][kk];
      acc[0][0] += a0 * bv.x; acc[0][1] += a0 * bv.y;
      acc[0][2] += a0 * bv.z; acc[0][3] += a0 * bv.w;
      acc[1][0] += a1 * bv.x; acc[1][1] += a1 * bv.y;
      acc[1][2] += a1 * bv.z; acc[1][3] += a1 * bv.w;
    }
  }
  const float* bias = which ? bkv : bq;
  float* dst = qk + ((size_t)which * NB + b) * 64 * ND;
  #pragma unroll
  for (int i2 = 0; i2 < 2; ++i2)
    #pragma unroll
    for (int j = 0; j < 4; ++j)
      dst[(ty * 2 + i2) * ND + h * 64 + tx * 4 + j] =
          acc[i2][j] + bias[h * 64 + tx * 4 + j];
}

// ---------------- k1b: scores + softmax -> attn (B,12,64,64) f32 ----------------
__global__ __launch_bounds__(256) void k1b_attn(const float* __restrict__ qk,
                                                float* __restrict__ attn) {
  int h = blockIdx.x, b = blockIdx.y;
  __shared__ float qs[64][68];
  __shared__ float ks[64][68];
  __shared__ float sc[64][68];
  __shared__ float rm[64], rs[64];
  int tid = threadIdx.x;
  #pragma unroll
  for (int p = 0; p < 16; ++p) {
    int i = p * 256 + tid;
    int r = i >> 6, c = i & 63;
    qs[r][c] = qk[(size_t)b * 64 * ND + r * ND + h * 64 + c];
    ks[r][c] = qk[(size_t)(NB + b) * 64 * ND + r * ND + h * 64 + c];
  }
  __syncthreads();
  int tx = tid & 15, ty = tid >> 4;
  float a[4][4] = {};
  #pragma unroll 8
  for (int kk = 0; kk < 64; ++kk) {
    float qv[4], kv[4];
    #pragma unroll
    for (int i = 0; i < 4; ++i) qv[i] = qs[ty * 4 + i][kk];
    #pragma unroll
    for (int j = 0; j < 4; ++j) kv[j] = ks[tx * 4 + j][kk];
    #pragma unroll
    for (int i = 0; i < 4; ++i)
      #pragma unroll
      for (int j = 0; j < 4; ++j) a[i][j] += qv[i] * kv[j];
  }
  #pragma unroll
  for (int i = 0; i < 4; ++i)
    #pragma unroll
    for (int j = 0; j < 4; ++j)
      sc[ty * 4 + i][tx * 4 + j] = a[i][j] * SCALE;
  __syncthreads();
  if (tid < 64) {
    float m = -1e30f;
    for (int z = 0; z < 64; ++z) m = fmaxf(m, sc[tid][z]);
    float s = 0.f;
    for (int z = 0; z < 64; ++z) s += expf(sc[tid][z] - m);
    rm[tid] = m;
    rs[tid] = 1.0f / s;
  }
  __syncthreads();
  #pragma unroll
  for (int p = 0; p < 16; ++p) {
    int i = p * 256 + tid;
    int r = i >> 6, c = i & 63;
    attn[((size_t)(b * NH + h) * 64 + r) * 64 + c] =
        expf(sc[r][c] - rm[r]) * rs[r];
  }
}

// ---------------- k2: PT[b][j][h*64+d] = sum_s attn[b,h,d,s]*Wo[h*64+s][j] (bf16) ----------------
__global__ __launch_bounds__(256) void k2_pt(const float* __restrict__ attn,
                                             const float* __restrict__ Wo,
                                             ushort* __restrict__ PT) {
  int jt = blockIdx.x, h = blockIdx.y, b = blockIdx.z;
  __shared__ float at[64][64];
  int tid = threadIdx.x;
  #pragma unroll
  for (int p = 0; p < 16; ++p) {
    int i = p * 256 + tid;
    int d = i >> 6, s = i & 63;
    at[d][s] = attn[((size_t)(b * NH + h) * 64 + d) * 64 + s];
  }
  __syncthreads();
  int tx = tid & 31;  // j group (x4)
  int ty = tid >> 5;  // d group (x8)
  int j0 = jt * 128 + tx * 4;
  float acc[8][4] = {};
  for (int s = 0; s < 64; ++s) {
    float4 w = *(const float4*)&Wo[(size_t)(h * 64 + s) * ND + j0];
    #pragma unroll
    for (int dd = 0; dd < 8; ++dd) {
      float av = at[ty * 8 + dd][s];
      acc[dd][0] += av * w.x; acc[dd][1] += av * w.y;
      acc[dd][2] += av * w.z; acc[dd][3] += av * w.w;
    }
  }
  #pragma unroll
  for (int jj = 0; jj < 4; ++jj) {
    ushort tmp[8];
    #pragma unroll
    for (int dd = 0; dd < 8; ++dd) tmp[dd] = f2b(acc[dd][jj]);
    *(uint4*)&PT[(size_t)b * ND * ND + (size_t)(j0 + jj) * ND + h * 64 + ty * 8] =
        *(const uint4*)tmp;
  }
}

// ---------------- k2b1: bvA[b][h*64+s] = sum_d bv[h*64+d]*attn[b,h,d,s] ----------------
__global__ __launch_bounds__(256) void k2b1_bva(const float* __restrict__ attn,
                                                const float* __restrict__ bkv,
                                                float* __restrict__ bvA) {
  int b = blockIdx.x;
  int tid = threadIdx.x;
  for (int i = tid; i < ND; i += 256) {
    int h = i >> 6, s = i & 63;
    const float* at = attn + (size_t)(b * NH + h) * 64 * 64;
    float acc = 0.f;
    #pragma unroll 8
    for (int d = 0; d < 64; ++d) acc += bkv[768 + h * 64 + d] * at[d * 64 + s];
    bvA[b * ND + i] = acc;
  }
}

// ---------------- k2b2: cvec[b][j] = sum_e bvA[b][e]*Wo[e][j] + bo[j] ----------------
__global__ __launch_bounds__(256) void k2b2_cvec(const float* __restrict__ bvA,
                                                 const float* __restrict__ Wo,
                                                 const float* __restrict__ bo,
                                                 float* __restrict__ cvec) {
  int jt = blockIdx.x, b = blockIdx.y;
  int tid = threadIdx.x;
  __shared__ float bl[768];
  __shared__ f32x4 red[256];
  for (int i = tid; i < ND; i += 256) bl[i] = bvA[b * ND + i];
  __syncthreads();
  int jq = tid & 31;   // j quad
  int es = tid >> 5;   // e split 0..7
  int j0 = jt * 128 + jq * 4;
  f32x4 acc = {0.f, 0.f, 0.f, 0.f};
  #pragma unroll 8
  for (int e = es * 96; e < es * 96 + 96; ++e) {
    float4 w = *(const float4*)&Wo[(size_t)e * ND + j0];
    float bv = bl[e];
    acc[0] += bv * w.x; acc[1] += bv * w.y;
    acc[2] += bv * w.z; acc[3] += bv * w.w;
  }
  red[tid] = acc;
  __syncthreads();
  if (tid < 32) {
    f32x4 s = red[tid];
    #pragma unroll
    for (int k = 1; k < 8; ++k) {
      f32x4 r = red[tid + 32 * k];
      s[0] += r[0]; s[1] += r[1]; s[2] += r[2]; s[3] += r[3];
    }
    #pragma unroll
    for (int c = 0; c < 4; ++c)
      cvec[b * ND + j0 + c] = s[c] + bo[j0 + c];
  }
}

// ---------------- k3: MT[b][j][c] = sum_e PT[b][j][e]*Wvb[c][e] + (j==c) ----------------
// dbuf GLDS pipeline; LDS chunk swizzle via pre-swizzled GLOBAL source
// (GLDS dest must stay linear), chunk' = q ^ ((row>>1)&3); read with same XOR.
__global__ __launch_bounds__(256, 3) void k3_gemm(const ushort* __restrict__ PT,
                                                  const ushort* __restrict__ Wvb,
                                                  ushort* __restrict__ MT) {
  int b = blockIdx.z, rowt = blockIdx.y, colt = blockIdx.x;
  const ushort* Ag = PT + (size_t)b * ND * ND + (size_t)rowt * 128 * ND;
  const ushort* Bg = Wvb + (size_t)colt * 128 * ND;
  ushort* Cout = MT + (size_t)b * ND * ND + (size_t)rowt * 128 * ND + colt * 128;

  __shared__ ushort As[2][128 * 32];
  __shared__ ushort Bs[2][128 * 32];
  int tid = threadIdx.x, w = tid >> 6, lane = tid & 63;
  int wr = (w >> 1) * 64, wc = (w & 1) * 64;
  int l15 = lane & 15, l4 = lane >> 4;
  int r0 = lane >> 2, q = lane & 3;  // staging: 4 lanes/row, 16B each

  f32x4 acc[4][4];
  #pragma unroll
  for (int mi = 0; mi < 4; ++mi)
    #pragma unroll
    for (int ni = 0; ni < 4; ++ni) acc[mi][ni] = {0.f, 0.f, 0.f, 0.f};

  auto STAGE = [&](int bufi, int kk) {
    #pragma unroll
    for (int cc = 0; cc < 2; ++cc) {
      int c = w + cc * 4;          // wave-uniform chunk id 0..7
      int row = c * 16 + r0;
      int sq = (q ^ ((row >> 1) & 3)) * 8;  // pre-swizzled source chunk
      GLDS(&Ag[(size_t)row * ND + kk + sq], &As[bufi][c * 512]);
      GLDS(&Bg[(size_t)row * ND + kk + sq], &Bs[bufi][c * 512]);
    }
  };

  STAGE(0, 0);
  __syncthreads();
  int cur = 0;
  for (int t = 0; t < NKT; ++t) {
    if (t + 1 < NKT) STAGE(cur ^ 1, (t + 1) * 32);
    bf16x8 af[4], bfr[4];
    #pragma unroll
    for (int mi = 0; mi < 4; ++mi) {
      int r = wr + mi * 16 + l15;
      af[mi] = *(const bf16x8*)&As[cur][r * 32 + (l4 ^ ((r >> 1) & 3)) * 8];
    }
    #pragma unroll
    for (int ni = 0; ni < 4; ++ni) {
      int r = wc + ni * 16 + l15;
      bfr[ni] = *(const bf16x8*)&Bs[cur][r * 32 + (l4 ^ ((r >> 1) & 3)) * 8];
    }
    #pragma unroll
    for (int mi = 0; mi < 4; ++mi)
      #pragma unroll
      for (int ni = 0; ni < 4; ++ni)
        acc[mi][ni] = __builtin_amdgcn_mfma_f32_16x16x32_bf16(af[mi], bfr[ni],
                                                              acc[mi][ni], 0, 0, 0);
    __syncthreads();
    cur ^= 1;
  }
  bool diagt = (rowt == colt);
  #pragma unroll
  for (int mi = 0; mi < 4; ++mi)
    #pragma unroll
    for (int ni = 0; ni < 4; ++ni)
      #pragma unroll
      for (int j = 0; j < 4; ++j) {
        int r = wr + mi * 16 + l4 * 4 + j;
        int c = wc + ni * 16 + l15;
        float v = acc[mi][ni][j] + ((diagt && r == c) ? 1.0f : 0.0f);
        Cout[(size_t)r * ND + c] = f2b(v);
      }
}

// ---------------- k4: out[b] = y[b] @ (M_b + I) + cvec[b] ----------------
// 128x128 tiles, 768 blocks (3/CU, all resident), XCD-chunked swizzle
// (XCD x handles exactly batch x). A: raw f32 y via GLDS with granule
// swizzle slot = g ^ (row&7) (pre-swizzled source); f32->bf16 on LDS read.
// B: bf16 MT via GLDS with k3's swizzle.
__global__ __launch_bounds__(256, 3) void k4_gemm(const float* __restrict__ y,
                                                  const ushort* __restrict__ MT,
                                                  const float* __restrict__ cvec,
                                                  float* __restrict__ out) {
  int flat = blockIdx.x;                    // 0..767
  int work = (flat & 7) * 96 + (flat >> 3); // bijective (768%8==0)
  int b = work / 96;
  int rem = work % 96;
  int rowt = rem / 6;   // 16 row tiles of 128
  int colt = rem % 6;   // 6 col tiles of 128
  const float* Ag = y + (size_t)b * NT * ND + (size_t)rowt * 128 * ND;
  const ushort* Bg = MT + (size_t)b * ND * ND + (size_t)colt * 128 * ND;
  float* Out = out + (size_t)b * NT * ND;

  __shared__ float Asf[2][128 * 32];  // 16 KiB each
  __shared__ ushort Bs[2][128 * 32];  // 8 KiB each
  int tid = threadIdx.x, w = tid >> 6, lane = tid & 63;
  int wr = (w >> 1) * 64, wc = (w & 1) * 64;
  int l15 = lane & 15, l4 = lane >> 4;
  int r0b = lane >> 2, qb = lane & 3;                  // B staging
  int r0a = lane >> 3, qa = (lane & 7) ^ (lane >> 3);  // A staging (pre-swz src)

  f32x4 acc[4][4];
  #pragma unroll
  for (int mi = 0; mi < 4; ++mi)
    #pragma unroll
    for (int ni = 0; ni < 4; ++ni) acc[mi][ni] = {0.f, 0.f, 0.f, 0.f};

  // A: 16 x 1KB wave-uniform chunks (8 rows x 8 granules of 16B each).
  // LDS slot j of row r holds global granule j ^ (r&7).
  auto ASTAGE = [&](int bufi, int kk) {
    #pragma unroll
    for (int cc = 0; cc < 4; ++cc) {
      int c = w + cc * 4;          // 0..15
      int row = c * 8 + r0a;
      GLDS(&Ag[(size_t)row * ND + kk + qa * 4], &Asf[bufi][c * 256]);
    }
  };
  // B: 8 x 1KB chunks (16 rows x 4 granules), k3-style swizzle.
  auto BSTAGE = [&](int bufi, int kk) {
    #pragma unroll
    for (int cc = 0; cc < 2; ++cc) {
      int c = w + cc * 4;
      int row = c * 16 + r0b;
      int sq = (qb ^ ((row >> 1) & 3)) * 8;
      GLDS(&Bg[(size_t)row * ND + kk + sq], &Bs[bufi][c * 512]);
    }
  };

  ASTAGE(0, 0);
  BSTAGE(0, 0);
  __syncthreads();
  int cur = 0;
  for (int t = 0; t < NKT; ++t) {
    if (t + 1 < NKT) { ASTAGE(cur ^ 1, (t + 1) * 32); BSTAGE(cur ^ 1, (t + 1) * 32); }
    bf16x8 af[4], bfr[4];
    #pragma unroll
    for (int mi = 0; mi < 4; ++mi) {
      int r = wr + mi * 16 + l15;
      int s0 = (l4 * 2) ^ (r & 7);
      int s1 = (l4 * 2 + 1) ^ (r & 7);
      f32x4 a0 = *(const f32x4*)&Asf[cur][r * 32 + s0 * 4];
      f32x4 a1 = *(const f32x4*)&Asf[cur][r * 32 + s1 * 4];
      ushort u[8];
      #pragma unroll
      for (int e = 0; e < 4; ++e) { u[e] = f2b(a0[e]); u[4 + e] = f2b(a1[e]); }
      af[mi] = *(const bf16x8*)u;
    }
    #pragma unroll
    for (int ni = 0; ni < 4; ++ni) {
      int r = wc + ni * 16 + l15;
      bfr[ni] = *(const bf16x8*)&Bs[cur][r * 32 + (l4 ^ ((r >> 1) & 3)) * 8];
    }
    #pragma unroll
    for (int mi = 0; mi < 4; ++mi)
      #pragma unroll
      for (int ni = 0; ni < 4; ++ni)
        acc[mi][ni] = __builtin_amdgcn_mfma_f32_16x16x32_bf16(af[mi], bfr[ni],
                                                              acc[mi][ni], 0, 0, 0);
    __syncthreads();
    cur ^= 1;
  }
  #pragma unroll
  for (int mi = 0; mi < 4; ++mi)
    #pragma unroll
    for (int ni = 0; ni < 4; ++ni) {
      int gc = colt * 128 + wc + ni * 16 + l15;
      float cv = cvec[b * ND + gc];
      #pragma unroll
      for (int j = 0; j < 4; ++j) {
        int gr = rowt * 128 + wr + mi * 16 + l4 * 4 + j;
        Out[(size_t)gr * ND + gc] = acc[mi][ni][j] + cv;
      }
    }
}

extern "C" void kernel_launch(void* const* d_in, const int* in_sizes, int n_in,
                              void* d_out, int out_size, void* d_ws, size_t ws_size,
                              hipStream_t stream) {
  const float* x = (const float*)d_in[0];
  const float* y = (const float*)d_in[1];
  const float* Wq = (const float*)d_in[2];
  const float* bq = (const float*)d_in[3];
  const float* Wkv = (const float*)d_in[4];
  const float* bkv = (const float*)d_in[5];
  const float* Wo = (const float*)d_in[6];
  const float* bo = (const float*)d_in[7];
  float* out = (float*)d_out;

  char* ws = (char*)d_ws;
  float* qk    = (float*)(ws + 0);          // 2*8*64*768*4  = 3,145,728
  float* attn  = (float*)(ws + 3145728);    // 8*12*64*64*4  = 1,572,864
  float* cvec  = (float*)(ws + 4718592);    // 8*768*4       = 24,576
  ushort* Wvb  = (ushort*)(ws + 4743168);   // 768*768*2     = 1,179,648
  ushort* PT   = (ushort*)(ws + 5922816);   // 8*768*768*2   = 9,437,184
  ushort* MT   = (ushort*)(ws + 15360000);  // 8*768*768*2   = 9,437,184
  float* bvA   = (float*)(ws + 0);          // reuses dead qk region after k1b

  k0_prep<<<dim3(2304), 256, 0, stream>>>(Wkv, Wvb);
  k1a_qk<<<dim3(NH, NB, 2), 512, 0, stream>>>(x, y, Wq, bq, Wkv, bkv, qk);
  k1b_attn<<<dim3(NH, NB), 256, 0, stream>>>(qk, attn);
  k2_pt<<<dim3(6, NH, NB), 256, 0, stream>>>(attn, Wo, PT);
  k2b1_bva<<<dim3(NB), 256, 0, stream>>>(attn, bkv, bvA);
  k2b2_cvec<<<dim3(6, NB), 256, 0, stream>>>(bvA, Wo, bo, cvec);
  k3_gemm<<<dim3(6, 6, NB), 256, 0, stream>>>(PT, Wvb, MT);
  k4_gemm<<<dim3(768), 256, 0, stream>>>(y, MT, cvec, out);
}